// Round 1
// baseline (696.669 us; speedup 1.0000x reference)
//
#include <hip/hip_runtime.h>
#include <hip/hip_bf16.h>

// MSA: B=8,S=4096,D=1024,H=16,DH=64. Softmax over HEAD axis per token (16x16).
// Pipeline: convert->fp16, fused QKV GEMM (N=3072), per-token attention, out GEMM.

#define DEV static __device__ __forceinline__

typedef __attribute__((ext_vector_type(8))) _Float16 fp16x8;
typedef __attribute__((ext_vector_type(4))) float f32x4;

DEV unsigned short f2h(float f) {
    union { _Float16 h; unsigned short u; } c;
    c.h = (_Float16)f;
    return c.u;
}
DEV float h2f(unsigned short u) {
    union { _Float16 h; unsigned short u; } c;
    c.u = u;
    return (float)c.h;
}

DEV void gl_lds16(const void* g, void* l) {
    __builtin_amdgcn_global_load_lds(
        (const __attribute__((address_space(1))) unsigned int*)g,
        (__attribute__((address_space(3))) unsigned int*)l, 16, 0, 0);
}

// ---------------- kernel 0: fp32 -> fp16 conversion / packing ----------------
// Xb [32768][1024] fp16; Wb = [wq;wk;wv] [3072][1024] fp16; Wob [1024][1024] fp16;
// biasc [3072] fp32 = [bq;bk;bv]
__global__ __launch_bounds__(256) void k_convert(
    const float* __restrict__ x,
    const float* __restrict__ wq, const float* __restrict__ wk,
    const float* __restrict__ wv, const float* __restrict__ wo,
    const float* __restrict__ bq, const float* __restrict__ bk,
    const float* __restrict__ bv,
    unsigned short* __restrict__ Xb, unsigned short* __restrict__ Wb,
    unsigned short* __restrict__ Wob, float* __restrict__ biasc)
{
    const int NX = 33554432 / 4;   // x float4 chunks
    const int NW = 3145728 / 4;    // wq+wk+wv chunks (262144 each)
    const int NO = 1048576 / 4;    // wo chunks
    const int NB = 3072 / 4;       // bias chunks (256 each)
    const int total = NX + NW + NO + NB;
    for (int c = blockIdx.x * blockDim.x + threadIdx.x; c < total;
         c += gridDim.x * blockDim.x) {
        if (c < NX) {
            float4 v = ((const float4*)x)[c];
            uint2 u;
            u.x = f2h(v.x) | ((unsigned int)f2h(v.y) << 16);
            u.y = f2h(v.z) | ((unsigned int)f2h(v.w) << 16);
            ((uint2*)Xb)[c] = u;
        } else if (c < NX + NW) {
            int e = c - NX;
            const float* w = (e < 262144) ? wq : (e < 524288) ? wk : wv;
            int off = e & 262143;
            float4 v = ((const float4*)w)[off];
            uint2 u;
            u.x = f2h(v.x) | ((unsigned int)f2h(v.y) << 16);
            u.y = f2h(v.z) | ((unsigned int)f2h(v.w) << 16);
            ((uint2*)Wb)[e] = u;
        } else if (c < NX + NW + NO) {
            int e = c - NX - NW;
            float4 v = ((const float4*)wo)[e];
            uint2 u;
            u.x = f2h(v.x) | ((unsigned int)f2h(v.y) << 16);
            u.y = f2h(v.z) | ((unsigned int)f2h(v.w) << 16);
            ((uint2*)Wob)[e] = u;
        } else {
            int e = c - NX - NW - NO;               // 0..767
            const float* b = (e < 256) ? bq : (e < 512) ? bk : bv;
            int off = e & 255;
            ((float4*)biasc)[e] = ((const float4*)b)[off];
        }
    }
}

// ---------------- GEMM: C[M][N] = A[M][K] * B[N][K]^T + bias, K=1024 --------
// m97 structure: 128x128 tile, BK=32, 4 waves (2x2 of 64x64), 16x16x32 MFMA,
// global_load_lds width 16. A row stride = LDA (3072 for strided ctx reads).
template <int LDA, bool OUT_F16>
__global__ __launch_bounds__(256) void k_gemm_bt(
    const unsigned short* __restrict__ A,   // [M][LDA] fp16 (K=1024 cols used)
    const unsigned short* __restrict__ B,   // [N][1024] fp16
    const float* __restrict__ bias,         // [N] fp32
    unsigned short* __restrict__ Ch,        // fp16 out (if OUT_F16)
    float* __restrict__ Cf,                 // fp32 out (else)
    int ldc)
{
    __shared__ __align__(16) unsigned short As[128 * 32];
    __shared__ __align__(16) unsigned short Bs[128 * 32];

    const int tid  = threadIdx.x;
    const int lane = tid & 63;
    const int w    = tid >> 6;
    const int wr   = w >> 1, wc = w & 1;
    const int quad = lane >> 4;
    const int lr   = lane & 15;

    const int m0 = blockIdx.y * 128;
    const int n0 = blockIdx.x * 128;

    f32x4 acc[4][4];
#pragma unroll
    for (int i = 0; i < 4; ++i)
#pragma unroll
        for (int j = 0; j < 4; ++j) {
            f32x4 z = {0.f, 0.f, 0.f, 0.f};
            acc[i][j] = z;
        }

    // staging: 512 16B chunks per tile, 2 per thread per tile
    const int id0 = tid, id1 = tid + 256;
    const int ar0 = id0 >> 2, ac0 = (id0 & 3) * 8;
    const int ar1 = id1 >> 2, ac1 = (id1 & 3) * 8;
    const unsigned short* Arow0 = A + (size_t)(m0 + ar0) * LDA + ac0;
    const unsigned short* Arow1 = A + (size_t)(m0 + ar1) * LDA + ac1;
    const unsigned short* Brow0 = B + (size_t)(n0 + ar0) * 1024 + ac0;
    const unsigned short* Brow1 = B + (size_t)(n0 + ar1) * 1024 + ac1;

    for (int k0 = 0; k0 < 1024; k0 += 32) {
        __syncthreads();                        // LDS free (prev compute done)
        gl_lds16(Arow0 + k0, (char*)As + id0 * 16);
        gl_lds16(Arow1 + k0, (char*)As + id1 * 16);
        gl_lds16(Brow0 + k0, (char*)Bs + id0 * 16);
        gl_lds16(Brow1 + k0, (char*)Bs + id1 * 16);
        asm volatile("s_waitcnt vmcnt(0)" ::: "memory");
        __syncthreads();                        // LDS filled

        fp16x8 a[4], b[4];
#pragma unroll
        for (int i = 0; i < 4; ++i)
            a[i] = *(const fp16x8*)(const void*)&As[(wr * 64 + i * 16 + lr) * 32 + quad * 8];
#pragma unroll
        for (int j = 0; j < 4; ++j)
            b[j] = *(const fp16x8*)(const void*)&Bs[(wc * 64 + j * 16 + lr) * 32 + quad * 8];
#pragma unroll
        for (int i = 0; i < 4; ++i)
#pragma unroll
            for (int j = 0; j < 4; ++j)
                acc[i][j] = __builtin_amdgcn_mfma_f32_16x16x32_f16(a[i], b[j], acc[i][j], 0, 0, 0);
    }

    // epilogue: C/D layout col = lane&15, row = quad*4 + reg
    float bj[4];
#pragma unroll
    for (int j = 0; j < 4; ++j) bj[j] = bias[n0 + wc * 64 + j * 16 + lr];
#pragma unroll
    for (int i = 0; i < 4; ++i) {
        const int mrow = m0 + wr * 64 + i * 16 + quad * 4;
#pragma unroll
        for (int j = 0; j < 4; ++j) {
            const int ncol = n0 + wc * 64 + j * 16 + lr;
#pragma unroll
            for (int r = 0; r < 4; ++r) {
                float v = acc[i][j][r] + bj[j];
                if (OUT_F16)
                    Ch[(size_t)(mrow + r) * ldc + ncol] = f2h(v);
                else
                    Cf[(size_t)(mrow + r) * ldc + ncol] = v;
            }
        }
    }
}

// ---------------- kernel 2: per-token 16x16 head attention ------------------
// One wave per token. qkv row = [q(1024)|k(1024)|v(1024)] fp16. ctx overwrites
// the q slot (safe: wave owns the token, q already copied to LDS).
__global__ __launch_bounds__(256) void k_attn(unsigned short* __restrict__ qkv)
{
    __shared__ __align__(16) float sq[4][3072];
    __shared__ __align__(16) float sp[4][16 * 17];

    const int tid = threadIdx.x;
    const int wv  = tid >> 6;
    const int l   = tid & 63;
    const int t   = blockIdx.x * 4 + wv;
    unsigned short* tok = qkv + (size_t)t * 3072;

    // load 3072 fp16 -> fp32 LDS (96B/lane, coalesced)
#pragma unroll
    for (int i = 0; i < 6; ++i) {
        const int e = i * 512 + l * 8;
        uint4 u = *(const uint4*)(tok + e);
        unsigned int uu[4] = {u.x, u.y, u.z, u.w};
#pragma unroll
        for (int c = 0; c < 4; ++c) {
            sq[wv][e + 2 * c]     = h2f((unsigned short)(uu[c] & 0xffff));
            sq[wv][e + 2 * c + 1] = h2f((unsigned short)(uu[c] >> 16));
        }
    }
    __syncthreads();

    const int h  = l >> 2;
    const int gq = (l & 3) * 4;           // this lane's 4 g values: gq..gq+3
    const float4* q4 = (const float4*)&sq[wv][h * 64];
    const float4* k4 = (const float4*)&sq[wv][1024];

    float s[4] = {0.f, 0.f, 0.f, 0.f};
#pragma unroll
    for (int d4 = 0; d4 < 16; ++d4) {
        float4 qv = q4[d4];
#pragma unroll
        for (int g = 0; g < 4; ++g) {
            float4 kv = k4[(gq + g) * 16 + d4];
            s[g] += qv.x * kv.x + qv.y * kv.y + qv.z * kv.z + qv.w * kv.w;
        }
    }
#pragma unroll
    for (int g = 0; g < 4; ++g) s[g] *= 0.125f;   // 1/sqrt(64)

    float m = fmaxf(fmaxf(s[0], s[1]), fmaxf(s[2], s[3]));
    m = fmaxf(m, __shfl_xor(m, 1, 64));
    m = fmaxf(m, __shfl_xor(m, 2, 64));
    float e4[4], sum = 0.f;
#pragma unroll
    for (int g = 0; g < 4; ++g) { e4[g] = __expf(s[g] - m); sum += e4[g]; }
    sum += __shfl_xor(sum, 1, 64);
    sum += __shfl_xor(sum, 2, 64);
    const float inv = 1.0f / sum;
#pragma unroll
    for (int g = 0; g < 4; ++g) sp[wv][h * 17 + gq + g] = e4[g] * inv;
    __syncthreads();

    // ctx[h][d] = sum_g p[h][g] * v[g][d]; lane covers d = db*16 .. db*16+15
    const int db = l & 3;
    const float4* v4 = (const float4*)&sq[wv][2048];
    float acc[16];
#pragma unroll
    for (int j = 0; j < 16; ++j) acc[j] = 0.f;
#pragma unroll
    for (int g = 0; g < 16; ++g) {
        const float p = sp[wv][h * 17 + g];
        const float4* vr = v4 + g * 16 + db * 4;
#pragma unroll
        for (int c = 0; c < 4; ++c) {
            float4 vvv = vr[c];
            acc[c * 4 + 0] += p * vvv.x;
            acc[c * 4 + 1] += p * vvv.y;
            acc[c * 4 + 2] += p * vvv.z;
            acc[c * 4 + 3] += p * vvv.w;
        }
    }

    unsigned short* dst = tok + h * 64 + db * 16;
    unsigned int o[8];
#pragma unroll
    for (int j = 0; j < 8; ++j)
        o[j] = f2h(acc[2 * j]) | ((unsigned int)f2h(acc[2 * j + 1]) << 16);
    uint4 o0 = {o[0], o[1], o[2], o[3]};
    uint4 o1 = {o[4], o[5], o[6], o[7]};
    ((uint4*)dst)[0] = o0;
    ((uint4*)dst)[1] = o1;
}

// ---------------- launch ----------------------------------------------------
extern "C" void kernel_launch(void* const* d_in, const int* in_sizes, int n_in,
                              void* d_out, int out_size, void* d_ws, size_t ws_size,
                              hipStream_t stream)
{
    (void)in_sizes; (void)n_in; (void)out_size;

    const float* x  = (const float*)d_in[0];
    const float* wq = (const float*)d_in[1];
    const float* bq = (const float*)d_in[2];
    const float* wk = (const float*)d_in[3];
    const float* bk = (const float*)d_in[4];
    const float* wv = (const float*)d_in[5];
    const float* bv = (const float*)d_in[6];
    const float* wo = (const float*)d_in[7];
    const float* bo = (const float*)d_in[8];

    // ws layout (bytes):
    //   QKV  [32768][3072] fp16 : 0          .. 201326592   (192 MiB)
    //   Xb   [32768][1024] fp16 : 201326592  .. 268435456   ( 64 MiB)
    //   Wb   [3072][1024]  fp16 : 268435456  .. 274726912   (  6 MiB)
    //   Wob  [1024][1024]  fp16 : 274726912  .. 276824064   (  2 MiB)
    //   bias [3072]        fp32 : 276824064  .. 276836352   ( 12 KiB)
    if (ws_size < 276836352ull) return;   // fail loudly (out stays poisoned)

    char* ws = (char*)d_ws;
    unsigned short* QKV  = (unsigned short*)(ws);
    unsigned short* Xb   = (unsigned short*)(ws + 201326592);
    unsigned short* Wb   = (unsigned short*)(ws + 268435456);
    unsigned short* Wob  = (unsigned short*)(ws + 274726912);
    float*          bqkv = (float*)(ws + 276824064);

    k_convert<<<2048, 256, 0, stream>>>(x, wq, wk, wv, wo, bq, bk, bv,
                                        Xb, Wb, Wob, bqkv);
    // QKV = Xb @ [wq;wk;wv]^T + bias  (M=32768, N=3072)
    k_gemm_bt<1024, true><<<dim3(24, 256), 256, 0, stream>>>(
        Xb, Wb, bqkv, QKV, nullptr, 3072);
    // per-token attention, ctx overwrites q slot
    k_attn<<<8192, 256, 0, stream>>>(QKV);
    // out = ctx @ wo^T + bo  (M=32768, N=1024, A strided by 3072)
    k_gemm_bt<3072, false><<<dim3(8, 256), 256, 0, stream>>>(
        QKV, Wob, bo, nullptr, (float*)d_out, 1024);
}

// Round 2
// 643.174 us; speedup vs baseline: 1.0832x; 1.0832x over previous
//
#include <hip/hip_runtime.h>
#include <hip/hip_bf16.h>

// MSA: B=8,S=4096,D=1024,H=16,DH=64. Softmax over HEAD axis per token (16x16).
// Pipeline: convert->fp16, fused QKV GEMM (N=3072), MFMA per-token attention,
// out GEMM (strided A over the qkv buffer, ctx written in-place to q slot).

#define DEV static __device__ __forceinline__

typedef __attribute__((ext_vector_type(8))) _Float16 fp16x8;
typedef __attribute__((ext_vector_type(4))) float f32x4;

DEV unsigned short f2h(float f) {
    union { _Float16 h; unsigned short u; } c;
    c.h = (_Float16)f;
    return c.u;
}
DEV _Float16 u2h(unsigned short u) {
    union { _Float16 h; unsigned short u; } c;
    c.u = u;
    return c.h;
}

DEV void gl_lds16(const void* g, void* l) {
    __builtin_amdgcn_global_load_lds(
        (const __attribute__((address_space(1))) unsigned int*)g,
        (__attribute__((address_space(3))) unsigned int*)l, 16, 0, 0);
}

// ---------------- kernel 0: fp32 -> fp16 conversion / packing ----------------
__global__ __launch_bounds__(256) void k_convert(
    const float* __restrict__ x,
    const float* __restrict__ wq, const float* __restrict__ wk,
    const float* __restrict__ wv, const float* __restrict__ wo,
    const float* __restrict__ bq, const float* __restrict__ bk,
    const float* __restrict__ bv,
    unsigned short* __restrict__ Xb, unsigned short* __restrict__ Wb,
    unsigned short* __restrict__ Wob, float* __restrict__ biasc)
{
    const int NX = 33554432 / 4;   // x float4 chunks
    const int NW = 3145728 / 4;    // wq+wk+wv chunks (262144 each)
    const int NO = 1048576 / 4;    // wo chunks
    const int NB = 3072 / 4;       // bias chunks (256 each)
    const int total = NX + NW + NO + NB;
    for (int c = blockIdx.x * blockDim.x + threadIdx.x; c < total;
         c += gridDim.x * blockDim.x) {
        if (c < NX) {
            float4 v = ((const float4*)x)[c];
            uint2 u;
            u.x = f2h(v.x) | ((unsigned int)f2h(v.y) << 16);
            u.y = f2h(v.z) | ((unsigned int)f2h(v.w) << 16);
            ((uint2*)Xb)[c] = u;
        } else if (c < NX + NW) {
            int e = c - NX;
            const float* w = (e < 262144) ? wq : (e < 524288) ? wk : wv;
            int off = e & 262143;
            float4 v = ((const float4*)w)[off];
            uint2 u;
            u.x = f2h(v.x) | ((unsigned int)f2h(v.y) << 16);
            u.y = f2h(v.z) | ((unsigned int)f2h(v.w) << 16);
            ((uint2*)Wb)[e] = u;
        } else if (c < NX + NW + NO) {
            int e = c - NX - NW;
            float4 v = ((const float4*)wo)[e];
            uint2 u;
            u.x = f2h(v.x) | ((unsigned int)f2h(v.y) << 16);
            u.y = f2h(v.z) | ((unsigned int)f2h(v.w) << 16);
            ((uint2*)Wob)[e] = u;
        } else {
            int e = c - NX - NW - NO;               // 0..767
            const float* b = (e < 256) ? bq : (e < 512) ? bk : bv;
            int off = e & 255;
            ((float4*)biasc)[e] = ((const float4*)b)[off];
        }
    }
}

// ---------------- GEMM: C[M][N] = A[M][K] * B[N][K]^T + bias, K=1024 --------
// m97 structure: 128x128 tile, BK=32, 4 waves (2x2 of 64x64), 16x16x32 MFMA,
// global_load_lds width 16. A row stride = LDA (3072 for strided ctx reads).
template <int LDA, bool OUT_F16>
__global__ __launch_bounds__(256) void k_gemm_bt(
    const unsigned short* __restrict__ A,   // [M][LDA] fp16 (K=1024 cols used)
    const unsigned short* __restrict__ B,   // [N][1024] fp16
    const float* __restrict__ bias,         // [N] fp32
    unsigned short* __restrict__ Ch,        // fp16 out (if OUT_F16)
    float* __restrict__ Cf,                 // fp32 out (else)
    int ldc)
{
    __shared__ __align__(16) unsigned short As[128 * 32];
    __shared__ __align__(16) unsigned short Bs[128 * 32];

    const int tid  = threadIdx.x;
    const int lane = tid & 63;
    const int w    = tid >> 6;
    const int wr   = w >> 1, wc = w & 1;
    const int quad = lane >> 4;
    const int lr   = lane & 15;

    const int m0 = blockIdx.y * 128;
    const int n0 = blockIdx.x * 128;

    f32x4 acc[4][4];
#pragma unroll
    for (int i = 0; i < 4; ++i)
#pragma unroll
        for (int j = 0; j < 4; ++j) {
            f32x4 z = {0.f, 0.f, 0.f, 0.f};
            acc[i][j] = z;
        }

    const int id0 = tid, id1 = tid + 256;
    const int ar0 = id0 >> 2, ac0 = (id0 & 3) * 8;
    const int ar1 = id1 >> 2, ac1 = (id1 & 3) * 8;
    const unsigned short* Arow0 = A + (size_t)(m0 + ar0) * LDA + ac0;
    const unsigned short* Arow1 = A + (size_t)(m0 + ar1) * LDA + ac1;
    const unsigned short* Brow0 = B + (size_t)(n0 + ar0) * 1024 + ac0;
    const unsigned short* Brow1 = B + (size_t)(n0 + ar1) * 1024 + ac1;

    for (int k0 = 0; k0 < 1024; k0 += 32) {
        __syncthreads();
        gl_lds16(Arow0 + k0, (char*)As + id0 * 16);
        gl_lds16(Arow1 + k0, (char*)As + id1 * 16);
        gl_lds16(Brow0 + k0, (char*)Bs + id0 * 16);
        gl_lds16(Brow1 + k0, (char*)Bs + id1 * 16);
        asm volatile("s_waitcnt vmcnt(0)" ::: "memory");
        __syncthreads();

        fp16x8 a[4], b[4];
#pragma unroll
        for (int i = 0; i < 4; ++i)
            a[i] = *(const fp16x8*)(const void*)&As[(wr * 64 + i * 16 + lr) * 32 + quad * 8];
#pragma unroll
        for (int j = 0; j < 4; ++j)
            b[j] = *(const fp16x8*)(const void*)&Bs[(wc * 64 + j * 16 + lr) * 32 + quad * 8];
#pragma unroll
        for (int i = 0; i < 4; ++i)
#pragma unroll
            for (int j = 0; j < 4; ++j)
                acc[i][j] = __builtin_amdgcn_mfma_f32_16x16x32_f16(a[i], b[j], acc[i][j], 0, 0, 0);
    }

    float bj[4];
#pragma unroll
    for (int j = 0; j < 4; ++j) bj[j] = bias[n0 + wc * 64 + j * 16 + lr];
#pragma unroll
    for (int i = 0; i < 4; ++i) {
        const int mrow = m0 + wr * 64 + i * 16 + quad * 4;
#pragma unroll
        for (int j = 0; j < 4; ++j) {
            const int ncol = n0 + wc * 64 + j * 16 + lr;
#pragma unroll
            for (int r = 0; r < 4; ++r) {
                float v = acc[i][j][r] + bj[j];
                if (OUT_F16)
                    Ch[(size_t)(mrow + r) * ldc + ncol] = f2h(v);
                else
                    Cf[(size_t)(mrow + r) * ldc + ncol] = v;
            }
        }
    }
}

// ---------------- kernel 2: per-token 16x16 head attention via MFMA ---------
// One wave per token. qkv row = [q(1024)|k(1024)|v(1024)] fp16.
// scores(16x16) = Q(16x64) K^T: 2 chained mfma_16x16x32_f16.
// softmax over g: butterfly shuffles within 16-lane groups (C layout).
// ctx(16x64) = P(16x16) V(16x64): 4 mfma (K=16: quads 2,3 carry zeros).
// ctx overwrites the q slot (wave owns the token; q already staged in LDS).
__global__ __launch_bounds__(256) void k_attn(unsigned short* __restrict__ qkv)
{
    // per-wave: qk = 32 rows x 72 halves (pad +8 -> 2-way-free frag reads)
    //           p  = 16 rows x 24 halves (K=16 real, pad for banks)
    __shared__ __align__(16) unsigned short sqk[4][32 * 72];
    __shared__ __align__(16) unsigned short sp[4][16 * 24];

    const int tid  = threadIdx.x;
    const int wv   = tid >> 6;
    const int l    = tid & 63;
    const int t    = blockIdx.x * 4 + wv;
    unsigned short* tok = qkv + (size_t)t * 3072;

    unsigned short* qk = sqk[wv];
    unsigned short* pp = sp[wv];

    const int quad = l >> 4;
    const int lr   = l & 15;

    // stage q,k (2048 halves) into padded LDS rows; global reads coalesced 1KiB/instr
    {
        const int d  = (l & 7) * 8;
        const int r0 = l >> 3;
#pragma unroll
        for (int i = 0; i < 4; ++i) {
            const int row = i * 8 + r0;
            uint4 u = *(const uint4*)(tok + i * 512 + l * 8);
            *(uint4*)&qk[row * 72 + d] = u;
        }
    }
    asm volatile("s_waitcnt lgkmcnt(0)" ::: "memory");

    // scores: A-frag = Q row lr, B-frag = K row lr (rows 16..31 of qk)
    f32x4 s = {0.f, 0.f, 0.f, 0.f};
#pragma unroll
    for (int ks = 0; ks < 2; ++ks) {
        fp16x8 aq = *(const fp16x8*)(const void*)&qk[lr * 72 + ks * 32 + quad * 8];
        fp16x8 bk = *(const fp16x8*)(const void*)&qk[(16 + lr) * 72 + ks * 32 + quad * 8];
        s = __builtin_amdgcn_mfma_f32_16x16x32_f16(aq, bk, s, 0, 0, 0);
    }

    // softmax over g: lane holds col g=lr, rows h=quad*4+r. Reduce across the
    // 16-lane group (xor 1,2,4,8 stays inside the quad group).
#pragma unroll
    for (int r = 0; r < 4; ++r) {
        float sv = s[r] * 0.125f;          // 1/sqrt(64)
        float m = sv;
        m = fmaxf(m, __shfl_xor(m, 1, 64));
        m = fmaxf(m, __shfl_xor(m, 2, 64));
        m = fmaxf(m, __shfl_xor(m, 4, 64));
        m = fmaxf(m, __shfl_xor(m, 8, 64));
        float e = __expf(sv - m);
        float su = e;
        su += __shfl_xor(su, 1, 64);
        su += __shfl_xor(su, 2, 64);
        su += __shfl_xor(su, 4, 64);
        su += __shfl_xor(su, 8, 64);
        float p = e * __builtin_amdgcn_rcpf(su);
        pp[(quad * 4 + r) * 24 + lr] = f2h(p);   // P[h][g]
    }
    asm volatile("s_waitcnt lgkmcnt(0)" ::: "memory");

    // P A-frag: A[m=lr][k=quad*8+j]; only k=0..15 real -> quads 2,3 zero
    fp16x8 pa;
    if (quad < 2) {
        pa = *(const fp16x8*)(const void*)&pp[lr * 24 + quad * 8];
    } else {
#pragma unroll
        for (int j = 0; j < 8; ++j) pa[j] = (_Float16)0.f;
    }

    // V B-frags direct from global: B[k=quad*8+j][n=nb*16+lr] = V[g][d];
    // quads 2,3 zero (k-pad). ctx = P*V, C layout: row h=quad*4+r, col d.
    const unsigned short* vbase = tok + 2048;
    f32x4 c[4];
#pragma unroll
    for (int nb = 0; nb < 4; ++nb) {
        fp16x8 bv;
#pragma unroll
        for (int j = 0; j < 8; ++j) bv[j] = (_Float16)0.f;
        if (quad < 2) {
#pragma unroll
            for (int j = 0; j < 8; ++j)
                bv[j] = u2h(vbase[(quad * 8 + j) * 64 + nb * 16 + lr]);
        }
        f32x4 z = {0.f, 0.f, 0.f, 0.f};
        c[nb] = __builtin_amdgcn_mfma_f32_16x16x32_f16(pa, bv, z, 0, 0, 0);
    }

    // write ctx into the q slot
#pragma unroll
    for (int nb = 0; nb < 4; ++nb)
#pragma unroll
        for (int r = 0; r < 4; ++r)
            tok[(quad * 4 + r) * 64 + nb * 16 + lr] = f2h(c[nb][r]);
}

// ---------------- launch ----------------------------------------------------
extern "C" void kernel_launch(void* const* d_in, const int* in_sizes, int n_in,
                              void* d_out, int out_size, void* d_ws, size_t ws_size,
                              hipStream_t stream)
{
    (void)in_sizes; (void)n_in; (void)out_size;

    const float* x  = (const float*)d_in[0];
    const float* wq = (const float*)d_in[1];
    const float* bq = (const float*)d_in[2];
    const float* wk = (const float*)d_in[3];
    const float* bk = (const float*)d_in[4];
    const float* wv = (const float*)d_in[5];
    const float* bv = (const float*)d_in[6];
    const float* wo = (const float*)d_in[7];
    const float* bo = (const float*)d_in[8];

    // ws layout (bytes):
    //   QKV  [32768][3072] fp16 : 0          .. 201326592   (192 MiB)
    //   Xb   [32768][1024] fp16 : 201326592  .. 268435456   ( 64 MiB)
    //   Wb   [3072][1024]  fp16 : 268435456  .. 274726912   (  6 MiB)
    //   Wob  [1024][1024]  fp16 : 274726912  .. 276824064   (  2 MiB)
    //   bias [3072]        fp32 : 276824064  .. 276836352   ( 12 KiB)
    if (ws_size < 276836352ull) return;

    char* ws = (char*)d_ws;
    unsigned short* QKV  = (unsigned short*)(ws);
    unsigned short* Xb   = (unsigned short*)(ws + 201326592);
    unsigned short* Wb   = (unsigned short*)(ws + 268435456);
    unsigned short* Wob  = (unsigned short*)(ws + 274726912);
    float*          bqkv = (float*)(ws + 276824064);

    k_convert<<<2048, 256, 0, stream>>>(x, wq, wk, wv, wo, bq, bk, bv,
                                        Xb, Wb, Wob, bqkv);
    k_gemm_bt<1024, true><<<dim3(24, 256), 256, 0, stream>>>(
        Xb, Wb, bqkv, QKV, nullptr, 3072);
    k_attn<<<8192, 256, 0, stream>>>(QKV);
    k_gemm_bt<3072, false><<<dim3(8, 256), 256, 0, stream>>>(
        QKV, Wob, bo, nullptr, (float*)d_out, 1024);
}

// Round 3
// 632.150 us; speedup vs baseline: 1.1021x; 1.0174x over previous
//
#include <hip/hip_runtime.h>
#include <hip/hip_bf16.h>

// MSA: B=8,S=4096,D=1024,H=16,DH=64. Softmax over HEAD axis per token (16x16).
// Pipeline: convert->fp16, fused QKV GEMM (N=3072), MFMA per-token attention
// (LDS-staged V, dense ctx output), out GEMM (dense A, LDA=1024).

#define DEV static __device__ __forceinline__

typedef __attribute__((ext_vector_type(8))) _Float16 fp16x8;
typedef __attribute__((ext_vector_type(4))) float f32x4;

DEV unsigned short f2h(float f) {
    union { _Float16 h; unsigned short u; } c;
    c.h = (_Float16)f;
    return c.u;
}

DEV void gl_lds16(const void* g, void* l) {
    __builtin_amdgcn_global_load_lds(
        (const __attribute__((address_space(1))) unsigned int*)g,
        (__attribute__((address_space(3))) unsigned int*)l, 16, 0, 0);
}

// ---------------- kernel 0: fp32 -> fp16 conversion / packing ----------------
__global__ __launch_bounds__(256) void k_convert(
    const float* __restrict__ x,
    const float* __restrict__ wq, const float* __restrict__ wk,
    const float* __restrict__ wv, const float* __restrict__ wo,
    const float* __restrict__ bq, const float* __restrict__ bk,
    const float* __restrict__ bv,
    unsigned short* __restrict__ Xb, unsigned short* __restrict__ Wb,
    unsigned short* __restrict__ Wob, float* __restrict__ biasc)
{
    const int NX = 33554432 / 4;   // x float4 chunks
    const int NW = 3145728 / 4;    // wq+wk+wv chunks (262144 each)
    const int NO = 1048576 / 4;    // wo chunks
    const int NB = 3072 / 4;       // bias chunks (256 each)
    const int total = NX + NW + NO + NB;
    for (int c = blockIdx.x * blockDim.x + threadIdx.x; c < total;
         c += gridDim.x * blockDim.x) {
        if (c < NX) {
            float4 v = ((const float4*)x)[c];
            uint2 u;
            u.x = f2h(v.x) | ((unsigned int)f2h(v.y) << 16);
            u.y = f2h(v.z) | ((unsigned int)f2h(v.w) << 16);
            ((uint2*)Xb)[c] = u;
        } else if (c < NX + NW) {
            int e = c - NX;
            const float* w = (e < 262144) ? wq : (e < 524288) ? wk : wv;
            int off = e & 262143;
            float4 v = ((const float4*)w)[off];
            uint2 u;
            u.x = f2h(v.x) | ((unsigned int)f2h(v.y) << 16);
            u.y = f2h(v.z) | ((unsigned int)f2h(v.w) << 16);
            ((uint2*)Wb)[e] = u;
        } else if (c < NX + NW + NO) {
            int e = c - NX - NW;
            float4 v = ((const float4*)wo)[e];
            uint2 u;
            u.x = f2h(v.x) | ((unsigned int)f2h(v.y) << 16);
            u.y = f2h(v.z) | ((unsigned int)f2h(v.w) << 16);
            ((uint2*)Wob)[e] = u;
        } else {
            int e = c - NX - NW - NO;               // 0..767
            const float* b = (e < 256) ? bq : (e < 512) ? bk : bv;
            int off = e & 255;
            ((float4*)biasc)[e] = ((const float4*)b)[off];
        }
    }
}

// ---------------- GEMM: C[M][N] = A[M][K] * B[N][K]^T + bias, K=1024 --------
// m97 structure: 128x128 tile, BK=32, 4 waves (2x2 of 64x64), 16x16x32 MFMA,
// global_load_lds width 16.
template <bool OUT_F16>
__global__ __launch_bounds__(256) void k_gemm_bt(
    const unsigned short* __restrict__ A,   // [M][1024] fp16
    const unsigned short* __restrict__ B,   // [N][1024] fp16
    const float* __restrict__ bias,         // [N] fp32
    unsigned short* __restrict__ Ch,        // fp16 out (if OUT_F16)
    float* __restrict__ Cf,                 // fp32 out (else)
    int ldc)
{
    __shared__ __align__(16) unsigned short As[128 * 32];
    __shared__ __align__(16) unsigned short Bs[128 * 32];

    const int tid  = threadIdx.x;
    const int lane = tid & 63;
    const int w    = tid >> 6;
    const int wr   = w >> 1, wc = w & 1;
    const int quad = lane >> 4;
    const int lr   = lane & 15;

    const int m0 = blockIdx.y * 128;
    const int n0 = blockIdx.x * 128;

    f32x4 acc[4][4];
#pragma unroll
    for (int i = 0; i < 4; ++i)
#pragma unroll
        for (int j = 0; j < 4; ++j) {
            f32x4 z = {0.f, 0.f, 0.f, 0.f};
            acc[i][j] = z;
        }

    const int id0 = tid, id1 = tid + 256;
    const int ar0 = id0 >> 2, ac0 = (id0 & 3) * 8;
    const int ar1 = id1 >> 2, ac1 = (id1 & 3) * 8;
    const unsigned short* Arow0 = A + (size_t)(m0 + ar0) * 1024 + ac0;
    const unsigned short* Arow1 = A + (size_t)(m0 + ar1) * 1024 + ac1;
    const unsigned short* Brow0 = B + (size_t)(n0 + ar0) * 1024 + ac0;
    const unsigned short* Brow1 = B + (size_t)(n0 + ar1) * 1024 + ac1;

    for (int k0 = 0; k0 < 1024; k0 += 32) {
        __syncthreads();
        gl_lds16(Arow0 + k0, (char*)As + id0 * 16);
        gl_lds16(Arow1 + k0, (char*)As + id1 * 16);
        gl_lds16(Brow0 + k0, (char*)Bs + id0 * 16);
        gl_lds16(Brow1 + k0, (char*)Bs + id1 * 16);
        asm volatile("s_waitcnt vmcnt(0)" ::: "memory");
        __syncthreads();

        fp16x8 a[4], b[4];
#pragma unroll
        for (int i = 0; i < 4; ++i)
            a[i] = *(const fp16x8*)(const void*)&As[(wr * 64 + i * 16 + lr) * 32 + quad * 8];
#pragma unroll
        for (int j = 0; j < 4; ++j)
            b[j] = *(const fp16x8*)(const void*)&Bs[(wc * 64 + j * 16 + lr) * 32 + quad * 8];
#pragma unroll
        for (int i = 0; i < 4; ++i)
#pragma unroll
            for (int j = 0; j < 4; ++j)
                acc[i][j] = __builtin_amdgcn_mfma_f32_16x16x32_f16(a[i], b[j], acc[i][j], 0, 0, 0);
    }

    float bj[4];
#pragma unroll
    for (int j = 0; j < 4; ++j) bj[j] = bias[n0 + wc * 64 + j * 16 + lr];
#pragma unroll
    for (int i = 0; i < 4; ++i) {
        const int mrow = m0 + wr * 64 + i * 16 + quad * 4;
#pragma unroll
        for (int j = 0; j < 4; ++j) {
            const int ncol = n0 + wc * 64 + j * 16 + lr;
#pragma unroll
            for (int r = 0; r < 4; ++r) {
                float v = acc[i][j][r] + bj[j];
                if (OUT_F16)
                    Ch[(size_t)(mrow + r) * ldc + ncol] = f2h(v);
                else
                    Cf[(size_t)(mrow + r) * ldc + ncol] = v;
            }
        }
    }
}

// ---------------- kernel 2: per-token 16x16 head attention via MFMA ---------
// One wave per token. qkv row = [q(1024)|k(1024)|v(1024)] fp16 (read-only).
// All global traffic coalesced uint4: 6 loads + 2 stores per lane.
// scores(16x16) = Q K^T : 2 mfma_16x16x32_f16 (frags from padded LDS rows).
// softmax over g: 16-lane butterfly shuffles in C layout.
// ctx(16x64) = P(16x16) V : 4 mfma; V transposed into LDS at stage time so
// B-frags are contiguous ds_read_b128. ctx repacked via LDS -> dense Ctx.
__global__ __launch_bounds__(256) void k_attn(
    const unsigned short* __restrict__ qkv,
    unsigned short* __restrict__ Ctx)           // [32768][1024] fp16
{
    // per-wave LDS (halves): qk 32x72 (q rows 0-15, k rows 16-31),
    // vt 64x24 (V^T: row d, col g), pp 16x24 (P). 8448 B/wave.
    __shared__ __align__(16) unsigned short sqk[4][32 * 72];
    __shared__ __align__(16) unsigned short svt[4][64 * 24];
    __shared__ __align__(16) unsigned short spp[4][16 * 24];

    const int tid  = threadIdx.x;
    const int wv   = tid >> 6;
    const int l    = tid & 63;
    const int t    = blockIdx.x * 4 + wv;
    const unsigned short* tok = qkv + (size_t)t * 3072;

    unsigned short* qk = sqk[wv];
    unsigned short* vt = svt[wv];
    unsigned short* pp = spp[wv];

    const int quad = l >> 4;
    const int lr   = l & 15;
    const int row8 = l >> 3;          // 0..7
    const int col8 = (l & 7) * 8;     // 0,8,..,56

    // stage q,k into padded rows (stride 72): 4 coalesced uint4 loads
#pragma unroll
    for (int i = 0; i < 4; ++i) {
        const int row = i * 8 + row8;
        uint4 u = *(const uint4*)(tok + i * 512 + l * 8);
        *(uint4*)&qk[row * 72 + col8] = u;
    }
    // stage V transposed: vt[d*24+g] = V[g][d]; 2 uint4 loads + 16 u16 writes
#pragma unroll
    for (int i = 0; i < 2; ++i) {
        const int g = i * 8 + row8;
        uint4 u = *(const uint4*)(tok + 2048 + i * 512 + l * 8);
        const unsigned short* hu = (const unsigned short*)&u;
#pragma unroll
        for (int c = 0; c < 8; ++c)
            vt[(col8 + c) * 24 + g] = hu[c];
    }
    asm volatile("s_waitcnt lgkmcnt(0)" ::: "memory");

    // scores: A-frag = Q row lr, B-frag = K row lr
    f32x4 s = {0.f, 0.f, 0.f, 0.f};
#pragma unroll
    for (int ks = 0; ks < 2; ++ks) {
        fp16x8 aq = *(const fp16x8*)(const void*)&qk[lr * 72 + ks * 32 + quad * 8];
        fp16x8 bk = *(const fp16x8*)(const void*)&qk[(16 + lr) * 72 + ks * 32 + quad * 8];
        s = __builtin_amdgcn_mfma_f32_16x16x32_f16(aq, bk, s, 0, 0, 0);
    }

    // softmax over g (lane holds col g=lr, rows h=quad*4+r)
#pragma unroll
    for (int r = 0; r < 4; ++r) {
        float sv = s[r] * 0.125f;          // 1/sqrt(64)
        float m = sv;
        m = fmaxf(m, __shfl_xor(m, 1, 64));
        m = fmaxf(m, __shfl_xor(m, 2, 64));
        m = fmaxf(m, __shfl_xor(m, 4, 64));
        m = fmaxf(m, __shfl_xor(m, 8, 64));
        float e = __expf(sv - m);
        float su = e;
        su += __shfl_xor(su, 1, 64);
        su += __shfl_xor(su, 2, 64);
        su += __shfl_xor(su, 4, 64);
        su += __shfl_xor(su, 8, 64);
        float p = e * __builtin_amdgcn_rcpf(su);
        pp[(quad * 4 + r) * 24 + lr] = f2h(p);   // P[h][g]
    }
    asm volatile("s_waitcnt lgkmcnt(0)" ::: "memory");

    // P A-frag: A[m=lr][k=quad*8+j]; K=16 real -> quads 2,3 zero
    fp16x8 pa;
    if (quad < 2) {
        pa = *(const fp16x8*)(const void*)&pp[lr * 24 + quad * 8];
    } else {
#pragma unroll
        for (int j = 0; j < 8; ++j) pa[j] = (_Float16)0.f;
    }

    // PV: B[k=quad*8+j][n=nb*16+lr] = vt[(nb*16+lr)*24 + quad*8 + j]
    f32x4 c[4];
#pragma unroll
    for (int nb = 0; nb < 4; ++nb) {
        fp16x8 bv;
        if (quad < 2) {
            bv = *(const fp16x8*)(const void*)&vt[(nb * 16 + lr) * 24 + quad * 8];
        } else {
#pragma unroll
            for (int j = 0; j < 8; ++j) bv[j] = (_Float16)0.f;
        }
        f32x4 z = {0.f, 0.f, 0.f, 0.f};
        c[nb] = __builtin_amdgcn_mfma_f32_16x16x32_f16(pa, bv, z, 0, 0, 0);
    }
    asm volatile("s_waitcnt lgkmcnt(0)" ::: "memory");  // q frags consumed

    // repack ctx (C layout -> row-major) through the q rows of LDS
#pragma unroll
    for (int nb = 0; nb < 4; ++nb)
#pragma unroll
        for (int r = 0; r < 4; ++r)
            qk[(quad * 4 + r) * 72 + nb * 16 + lr] = f2h(c[nb][r]);
    asm volatile("s_waitcnt lgkmcnt(0)" ::: "memory");

    unsigned short* dst = Ctx + (size_t)t * 1024;
#pragma unroll
    for (int i = 0; i < 2; ++i) {
        const int row = i * 8 + row8;
        uint4 u = *(const uint4*)&qk[row * 72 + col8];
        *(uint4*)(dst + row * 64 + col8) = u;
    }
}

// ---------------- launch ----------------------------------------------------
extern "C" void kernel_launch(void* const* d_in, const int* in_sizes, int n_in,
                              void* d_out, int out_size, void* d_ws, size_t ws_size,
                              hipStream_t stream)
{
    (void)in_sizes; (void)n_in; (void)out_size;

    const float* x  = (const float*)d_in[0];
    const float* wq = (const float*)d_in[1];
    const float* bq = (const float*)d_in[2];
    const float* wk = (const float*)d_in[3];
    const float* bk = (const float*)d_in[4];
    const float* wv = (const float*)d_in[5];
    const float* bv = (const float*)d_in[6];
    const float* wo = (const float*)d_in[7];
    const float* bo = (const float*)d_in[8];

    // ws layout (bytes):
    //   QKV  [32768][3072] fp16 : 0          .. 201326592   (192 MiB)
    //   Xb   [32768][1024] fp16 : 201326592  .. 268435456   ( 64 MiB)
    //        (reused as dense Ctx after the QKV GEMM has consumed it)
    //   Wb   [3072][1024]  fp16 : 268435456  .. 274726912   (  6 MiB)
    //   Wob  [1024][1024]  fp16 : 274726912  .. 276824064   (  2 MiB)
    //   bias [3072]        fp32 : 276824064  .. 276836352   ( 12 KiB)
    if (ws_size < 276836352ull) return;

    char* ws = (char*)d_ws;
    unsigned short* QKV  = (unsigned short*)(ws);
    unsigned short* Xb   = (unsigned short*)(ws + 201326592);
    unsigned short* Wb   = (unsigned short*)(ws + 268435456);
    unsigned short* Wob  = (unsigned short*)(ws + 274726912);
    float*          bqkv = (float*)(ws + 276824064);
    unsigned short* Ctx  = Xb;   // Xb dead after QKV GEMM (stream-ordered)

    k_convert<<<2048, 256, 0, stream>>>(x, wq, wk, wv, wo, bq, bk, bv,
                                        Xb, Wb, Wob, bqkv);
    k_gemm_bt<true><<<dim3(24, 256), 256, 0, stream>>>(
        Xb, Wb, bqkv, QKV, nullptr, 3072);
    k_attn<<<8192, 256, 0, stream>>>(QKV, Ctx);
    k_gemm_bt<false><<<dim3(8, 256), 256, 0, stream>>>(
        Ctx, Wob, bo, nullptr, (float*)d_out, 1024);
}